// Round 6
// baseline (251.917 us; speedup 1.0000x reference)
//
#include <hip/hip_runtime.h>
#include <hip/hip_bf16.h>

// DilatedAttention (b=4, n=8192, d=1024, w=2048, r=4):
// 16 independent 512x512 self-attentions at d=1024 over gathered tokens
// off + 4*j per segment. alphas==1 (idx unique), so output = scatter(att).
//
// Pipeline (4 kernels): gather(x->xg*scale, xgT) ; QK GEMM -> S bf16 ;
// rowwise softmax in-place -> P ; PV: stage 64x512 P-tile in LDS once,
// K-loop streams only B (xgT), nontemporal scatter store + fused zero-fill.

typedef __bf16 bf16_t;
typedef __bf16 bf16x8 __attribute__((ext_vector_type(8)));
typedef float floatx4 __attribute__((ext_vector_type(4)));

#define D_MODEL 1024
#define SEG_W   2048
#define RATE    4
#define M_SUB   512          // tokens per segment after dilation (w/r)
#define NTOK    8192
#define NSEGT   16           // batch(4) * segments(4)
#define XG_ELEMS ((long)NSEGT * M_SUB * D_MODEL)
#define QK_SCALE 0.17677669529663689f   // 1/sqrt(32); applied to Q and K

__device__ __forceinline__ void gload16(const bf16_t* g, bf16_t* l) {
    __builtin_amdgcn_global_load_lds(
        (const __attribute__((address_space(1))) void*)g,
        (__attribute__((address_space(3))) void*)l, 16, 0, 0);
}

// ---------------------------------------------------------------------------
// K1: gather x[b, s*2048 + off + 4i, :] -> xg bf16 [seg][i][d] (pre-scaled by
// 1/sqrt(32) so QK^T is auto-scaled by 1/32) and xgT bf16 [seg][d][i]
// (unscaled: V operand).
// ---------------------------------------------------------------------------
__global__ __launch_bounds__(256) void gather_kernel(
    const float* __restrict__ x, const int* __restrict__ hidp,
    bf16_t* __restrict__ xg, bf16_t* __restrict__ xgT)
{
    const int off = ((hidp[0] % RATE) + RATE) % RATE;
    const int bid = blockIdx.x;
    const int seg = bid >> 7;          // 0..15
    const int rem = bid & 127;
    const int it  = rem >> 4;          // i-tile 0..7
    const int dt  = rem & 15;          // d-tile 0..15
    const int b   = seg >> 2, s = seg & 3;

    __shared__ ushort tile[64][65];

    const int t  = threadIdx.x;
    const int r  = t >> 2;             // 0..63
    const int cq = (t & 3) << 4;       // 0,16,32,48

    union U8 { bf16x8 v; ushort u[8]; };

    {
        const int  i   = it * 64 + r;
        const long tok = (long)s * SEG_W + off + 4L * i;
        const float* src = x + ((long)b * NTOK + tok) * D_MODEL + dt * 64 + cq;
        float4 f0 = ((const float4*)src)[0];
        float4 f1 = ((const float4*)src)[1];
        float4 f2 = ((const float4*)src)[2];
        float4 f3 = ((const float4*)src)[3];
        U8 lo, hi, ls, hs;
        // unscaled (tile -> xgT)
        lo.v[0]=(bf16_t)f0.x; lo.v[1]=(bf16_t)f0.y; lo.v[2]=(bf16_t)f0.z; lo.v[3]=(bf16_t)f0.w;
        lo.v[4]=(bf16_t)f1.x; lo.v[5]=(bf16_t)f1.y; lo.v[6]=(bf16_t)f1.z; lo.v[7]=(bf16_t)f1.w;
        hi.v[0]=(bf16_t)f2.x; hi.v[1]=(bf16_t)f2.y; hi.v[2]=(bf16_t)f2.z; hi.v[3]=(bf16_t)f2.w;
        hi.v[4]=(bf16_t)f3.x; hi.v[5]=(bf16_t)f3.y; hi.v[6]=(bf16_t)f3.z; hi.v[7]=(bf16_t)f3.w;
        // scaled (xg: Q/K operand)
        ls.v[0]=(bf16_t)(f0.x*QK_SCALE); ls.v[1]=(bf16_t)(f0.y*QK_SCALE);
        ls.v[2]=(bf16_t)(f0.z*QK_SCALE); ls.v[3]=(bf16_t)(f0.w*QK_SCALE);
        ls.v[4]=(bf16_t)(f1.x*QK_SCALE); ls.v[5]=(bf16_t)(f1.y*QK_SCALE);
        ls.v[6]=(bf16_t)(f1.z*QK_SCALE); ls.v[7]=(bf16_t)(f1.w*QK_SCALE);
        hs.v[0]=(bf16_t)(f2.x*QK_SCALE); hs.v[1]=(bf16_t)(f2.y*QK_SCALE);
        hs.v[2]=(bf16_t)(f2.z*QK_SCALE); hs.v[3]=(bf16_t)(f2.w*QK_SCALE);
        hs.v[4]=(bf16_t)(f3.x*QK_SCALE); hs.v[5]=(bf16_t)(f3.y*QK_SCALE);
        hs.v[6]=(bf16_t)(f3.z*QK_SCALE); hs.v[7]=(bf16_t)(f3.w*QK_SCALE);
        bf16_t* dstg = xg + ((long)seg * M_SUB + i) * D_MODEL + dt * 64 + cq;
        *(bf16x8*)(dstg)     = ls.v;
        *(bf16x8*)(dstg + 8) = hs.v;
        #pragma unroll
        for (int j = 0; j < 8; ++j) { tile[r][cq + j] = lo.u[j]; tile[r][cq + 8 + j] = hi.u[j]; }
    }
    __syncthreads();
    {
        const int dc = r;
        const int iq = cq;
        U8 o0, o1;
        #pragma unroll
        for (int j = 0; j < 8; ++j) { o0.u[j] = tile[iq + j][dc]; o1.u[j] = tile[iq + 8 + j][dc]; }
        bf16_t* dstT = xgT + ((long)seg * D_MODEL + dt * 64 + dc) * M_SUB + it * 64 + iq;
        *(bf16x8*)(dstT)     = o0.v;
        *(bf16x8*)(dstT + 8) = o1.v;
    }
}

// ---------------------------------------------------------------------------
// K2: QK GEMM. S[seg][q][k] = sum_d xg[q][d]*xg[k][d] (pre-scaled), bf16 out.
// BM=64, BN=128, BK=64. grid = 16 segs * 8 mt * 4 nt = 512 blocks, 4 waves.
// XOR chunk swizzle: global 16B-chunk c of LDS row r lives at slot c^(r&7).
// ---------------------------------------------------------------------------
__global__ __launch_bounds__(256) void qk_kernel(
    const bf16_t* __restrict__ xg, bf16_t* __restrict__ S)
{
    const int bid = blockIdx.x;
    const int seg = bid >> 5;
    const int mt  = (bid >> 2) & 7;
    const int nt  = bid & 3;

    const int tid  = threadIdx.x;
    const int w    = tid >> 6;
    const int lane = tid & 63;
    const int l16  = lane & 15;
    const int quad = lane >> 4;
    const int wr   = w >> 1, wc = w & 1;
    const int rowin = lane >> 3;            // 0..7 row within 8-row round
    const int cswz  = ((lane & 7) ^ rowin) * 8;  // swizzled chunk offset (elems)
    const int rsw   = l16 & 7;              // fragment-row swizzle key

    __shared__ alignas(16) bf16_t As[64 * 64];    // 8 KB
    __shared__ alignas(16) bf16_t Bs[128 * 64];   // 16 KB

    const bf16_t* xseg = xg + (long)seg * M_SUB * D_MODEL;

    const bf16_t* ga0 = xseg + (long)(mt * 64 + w * 16 + rowin) * D_MODEL + cswz;
    const bf16_t* ga1 = ga0 + 8 * D_MODEL;
    const bf16_t* gb0 = xseg + (long)(nt * 128 + w * 32 + rowin) * D_MODEL + cswz;
    const bf16_t* gb1 = gb0 +  8 * D_MODEL;
    const bf16_t* gb2 = gb0 + 16 * D_MODEL;
    const bf16_t* gb3 = gb0 + 24 * D_MODEL;
    bf16_t* la0 = &As[(w * 16 + 0) * 64];
    bf16_t* la1 = &As[(w * 16 + 8) * 64];
    bf16_t* lb0 = &Bs[(w * 32 + 0) * 64];
    bf16_t* lb1 = &Bs[(w * 32 + 8) * 64];
    bf16_t* lb2 = &Bs[(w * 32 + 16) * 64];
    bf16_t* lb3 = &Bs[(w * 32 + 24) * 64];

    floatx4 acc[2][4];
    #pragma unroll
    for (int i = 0; i < 2; ++i)
        #pragma unroll
        for (int j = 0; j < 4; ++j) acc[i][j] = (floatx4){0.f, 0.f, 0.f, 0.f};

    for (int kk = 0; kk < D_MODEL; kk += 64) {
        __syncthreads();
        gload16(ga0 + kk, la0); gload16(ga1 + kk, la1);
        gload16(gb0 + kk, lb0); gload16(gb1 + kk, lb1);
        gload16(gb2 + kk, lb2); gload16(gb3 + kk, lb3);
        __syncthreads();

        #pragma unroll
        for (int ks = 0; ks < 2; ++ks) {
            bf16x8 Af[2], Bf[4];
            #pragma unroll
            for (int m2 = 0; m2 < 2; ++m2) {
                const int row = wr * 32 + m2 * 16 + l16;
                Af[m2] = *(const bf16x8*)&As[row * 64 + (((ks * 4 + quad) ^ rsw) * 8)];
            }
            #pragma unroll
            for (int n2 = 0; n2 < 4; ++n2) {
                const int row = wc * 64 + n2 * 16 + l16;
                Bf[n2] = *(const bf16x8*)&Bs[row * 64 + (((ks * 4 + quad) ^ rsw) * 8)];
            }
            #pragma unroll
            for (int m2 = 0; m2 < 2; ++m2)
                #pragma unroll
                for (int n2 = 0; n2 < 4; ++n2)
                    acc[m2][n2] = __builtin_amdgcn_mfma_f32_16x16x32_bf16(Af[m2], Bf[n2], acc[m2][n2], 0, 0, 0);
        }
    }

    bf16_t* Sseg = S + (long)seg * M_SUB * M_SUB;
    #pragma unroll
    for (int m2 = 0; m2 < 2; ++m2) {
        const int qrow = mt * 64 + wr * 32 + m2 * 16 + quad * 4;
        #pragma unroll
        for (int n2 = 0; n2 < 4; ++n2) {
            const int col = nt * 128 + wc * 64 + n2 * 16 + l16;
            #pragma unroll
            for (int rg = 0; rg < 4; ++rg)
                Sseg[(long)(qrow + rg) * M_SUB + col] = (bf16_t)acc[m2][n2][rg];
        }
    }
}

// ---------------------------------------------------------------------------
// K3: row-wise softmax in-place on S (bf16). 1 wave per 512-row.
// ---------------------------------------------------------------------------
__global__ __launch_bounds__(256) void softmax_kernel(bf16_t* __restrict__ S)
{
    const int row  = blockIdx.x * 4 + (threadIdx.x >> 6);
    const int lane = threadIdx.x & 63;
    bf16_t* p = S + (long)row * M_SUB + lane * 8;
    bf16x8 v = *(const bf16x8*)p;
    float f[8];
    #pragma unroll
    for (int j = 0; j < 8; ++j) f[j] = (float)v[j];
    float m = f[0];
    #pragma unroll
    for (int j = 1; j < 8; ++j) m = fmaxf(m, f[j]);
    #pragma unroll
    for (int d = 1; d < 64; d <<= 1) m = fmaxf(m, __shfl_xor(m, d, 64));
    float sum = 0.f;
    #pragma unroll
    for (int j = 0; j < 8; ++j) { f[j] = __expf(f[j] - m); sum += f[j]; }
    #pragma unroll
    for (int d = 1; d < 64; d <<= 1) sum += __shfl_xor(sum, d, 64);
    const float inv = 1.0f / sum;
    #pragma unroll
    for (int j = 0; j < 8; ++j) v[j] = (bf16_t)(f[j] * inv);
    *(bf16x8*)p = v;
}

// ---------------------------------------------------------------------------
// K4: PV GEMM, A-resident. Per block: stage P-tile [64 q-rows][512 k] into
// LDS once (xor-swizzled chunks), then K-loop streams only B (xgT); A-frags
// read from the resident tile. BM=64, BN=128, BK=64.
// grid = 16 segs * 8 mt * 8 nt = 1024 blocks, 4 waves, LDS 80 KB (2 blk/CU).
// Epilogue: nontemporal scatter + zero-fill of 3*64 non-idx rows x 128 cols.
// ---------------------------------------------------------------------------
__global__ __launch_bounds__(256) void pv_kernel(
    const bf16_t* __restrict__ P, const bf16_t* __restrict__ xgT,
    const int* __restrict__ hidp, float* __restrict__ out)
{
    const int off = ((hidp[0] % RATE) + RATE) % RATE;
    const int bid = blockIdx.x;
    const int seg = bid >> 6;          // 0..15
    const int mt  = (bid >> 3) & 7;    // 0..7  (64-row q-tile)
    const int nt  = bid & 7;           // 0..7  (128-col d-tile)
    const int b   = seg >> 2, s = seg & 3;

    const int tid  = threadIdx.x;
    const int w    = tid >> 6;
    const int lane = tid & 63;
    const int l16  = lane & 15;
    const int quad = lane >> 4;
    const int wr   = w >> 1, wc = w & 1;
    const int rowin = lane >> 3;
    const int cswz  = ((lane & 7) ^ rowin) * 8;
    const int rsw   = l16 & 7;

    __shared__ alignas(16) bf16_t Stile[64 * 512];   // 64 KB
    __shared__ alignas(16) bf16_t Bs[128 * 64];      // 16 KB

    // ---- stage P-tile once: lane L fetches global chunk L^(row&7) so
    // logical chunk c lands at LDS slot c^(row&7).
    const bf16_t* Prow0 = P + (long)seg * M_SUB * M_SUB + (long)(mt * 64) * M_SUB;
    #pragma unroll
    for (int i = 0; i < 16; ++i) {
        const int row = w * 16 + i;
        const bf16_t* g = Prow0 + (long)row * M_SUB + ((lane ^ (i & 7)) * 8);
        gload16(g, &Stile[row * 512]);
    }

    // ---- GEMM: A resident in Stile, B streamed. Wave tile 32x64 (2x4).
    const bf16_t* Bseg = xgT + (long)seg * D_MODEL * M_SUB + (long)nt * 128 * M_SUB;
    const bf16_t* gb0 = Bseg + (long)(w * 32 + rowin) * M_SUB + cswz;
    const bf16_t* gb1 = gb0 +  8 * M_SUB;
    const bf16_t* gb2 = gb0 + 16 * M_SUB;
    const bf16_t* gb3 = gb0 + 24 * M_SUB;
    bf16_t* lb0 = &Bs[(w * 32 + 0) * 64];
    bf16_t* lb1 = &Bs[(w * 32 + 8) * 64];
    bf16_t* lb2 = &Bs[(w * 32 + 16) * 64];
    bf16_t* lb3 = &Bs[(w * 32 + 24) * 64];

    floatx4 acc[2][4];
    #pragma unroll
    for (int i = 0; i < 2; ++i)
        #pragma unroll
        for (int j = 0; j < 4; ++j) acc[i][j] = (floatx4){0.f, 0.f, 0.f, 0.f};

    for (int kk = 0; kk < M_SUB; kk += 64) {
        __syncthreads();
        gload16(gb0 + kk, lb0); gload16(gb1 + kk, lb1);
        gload16(gb2 + kk, lb2); gload16(gb3 + kk, lb3);
        __syncthreads();

        const int kchunk = kk >> 3;        // 8 * kstep
        #pragma unroll
        for (int ks = 0; ks < 2; ++ks) {
            bf16x8 Af[2], Bf[4];
            #pragma unroll
            for (int m2 = 0; m2 < 2; ++m2) {
                const int row = wr * 32 + m2 * 16 + l16;
                Af[m2] = *(const bf16x8*)&Stile[row * 512 + (kchunk | ((ks * 4 + quad) ^ rsw)) * 8];
            }
            #pragma unroll
            for (int n2 = 0; n2 < 4; ++n2) {
                const int row = wc * 64 + n2 * 16 + l16;
                Bf[n2] = *(const bf16x8*)&Bs[row * 64 + (((ks * 4 + quad) ^ rsw) * 8)];
            }
            #pragma unroll
            for (int m2 = 0; m2 < 2; ++m2)
                #pragma unroll
                for (int n2 = 0; n2 < 4; ++n2)
                    acc[m2][n2] = __builtin_amdgcn_mfma_f32_16x16x32_bf16(Af[m2], Bf[n2], acc[m2][n2], 0, 0, 0);
        }
    }

    // ---- result scatter (nontemporal: not re-read)
    float* obase = out + (long)b * NTOK * D_MODEL;
    #pragma unroll
    for (int m2 = 0; m2 < 2; ++m2) {
        const int qrow0 = mt * 64 + wr * 32 + m2 * 16 + quad * 4;
        #pragma unroll
        for (int rg = 0; rg < 4; ++rg) {
            const long tok = (long)s * SEG_W + off + 4L * (qrow0 + rg);
            float* orow = obase + tok * D_MODEL;
            #pragma unroll
            for (int n2 = 0; n2 < 4; ++n2) {
                const int d = nt * 128 + wc * 64 + n2 * 16 + l16;
                __builtin_nontemporal_store(acc[m2][n2][rg], &orow[d]);
            }
        }
    }

    // ---- fused zero-fill: 3*64 non-idx rows x this block's 128 cols
    {
        const floatx4 z = {0.f, 0.f, 0.f, 0.f};
        const int zr = tid >> 5;        // 0..7
        const int zc = tid & 31;        // float4 chunk within 128 cols
        #pragma unroll 4
        for (int p = 0; p < 24; ++p) {
            const int j = p * 8 + zr;   // 0..191
            const int q = j / 3, e = j % 3;
            const int delta = e + (e >= off ? 1 : 0);
            const long tok = (long)s * SEG_W + 4L * (mt * 64 + q) + delta;
            float* dst = obase + tok * D_MODEL + nt * 128 + zc * 4;
            __builtin_nontemporal_store(z, (floatx4*)dst);
        }
    }
}

extern "C" void kernel_launch(void* const* d_in, const int* in_sizes, int n_in,
                              void* d_out, int out_size, void* d_ws, size_t ws_size,
                              hipStream_t stream) {
    const float* x   = (const float*)d_in[0];
    const int*   hid = (const int*)d_in[1];
    float*       out = (float*)d_out;
    bf16_t* xg  = (bf16_t*)d_ws;
    bf16_t* xgT = xg + XG_ELEMS;
    bf16_t* S   = xgT + XG_ELEMS;     // total ws: 2*16.78 + 8.39 = 41.9 MB

    gather_kernel<<<dim3(2048), dim3(256), 0, stream>>>(x, hid, xg, xgT);
    qk_kernel<<<dim3(512), dim3(256), 0, stream>>>(xg, S);
    softmax_kernel<<<dim3(2048), dim3(256), 0, stream>>>(S);
    pv_kernel<<<dim3(1024), dim3(256), 0, stream>>>(S, xgT, hid, out);
}

// Round 7
// 250.111 us; speedup vs baseline: 1.0072x; 1.0072x over previous
//
#include <hip/hip_runtime.h>
#include <hip/hip_bf16.h>

// DilatedAttention (b=4, n=8192, d=1024, w=2048, r=4):
// 16 independent 512x512 self-attentions at d=1024 over gathered tokens
// off + 4*j per segment. alphas==1 (idx unique), so output = scatter(att).
//
// Round 7: round-4 structure (streaming 128x128 pv, standalone softmax,
// prescaled gather) with 512-thread GEMM blocks: 2 blk/CU -> 16 waves/CU
// for 2x latency hiding on global_load_lds staging.

typedef __bf16 bf16_t;
typedef __bf16 bf16x8 __attribute__((ext_vector_type(8)));
typedef float floatx4 __attribute__((ext_vector_type(4)));

#define D_MODEL 1024
#define SEG_W   2048
#define RATE    4
#define M_SUB   512          // tokens per segment after dilation (w/r)
#define NTOK    8192
#define NSEGT   16           // batch(4) * segments(4)
#define XG_ELEMS ((long)NSEGT * M_SUB * D_MODEL)
#define QK_SCALE 0.17677669529663689f   // 1/sqrt(32); applied to Q and K copy

__device__ __forceinline__ void gload16(const bf16_t* g, bf16_t* l) {
    __builtin_amdgcn_global_load_lds(
        (const __attribute__((address_space(1))) void*)g,
        (__attribute__((address_space(3))) void*)l, 16, 0, 0);
}

// ---------------------------------------------------------------------------
// K1: gather x[b, s*2048 + off + 4i, :] -> xg bf16 [seg][i][d] (pre-scaled by
// 1/sqrt(32) so QK^T is auto-scaled by 1/32) and xgT bf16 [seg][d][i]
// (unscaled: V operand).
// ---------------------------------------------------------------------------
__global__ __launch_bounds__(256) void gather_kernel(
    const float* __restrict__ x, const int* __restrict__ hidp,
    bf16_t* __restrict__ xg, bf16_t* __restrict__ xgT)
{
    const int off = ((hidp[0] % RATE) + RATE) % RATE;
    const int bid = blockIdx.x;
    const int seg = bid >> 7;          // 0..15
    const int rem = bid & 127;
    const int it  = rem >> 4;          // i-tile 0..7
    const int dt  = rem & 15;          // d-tile 0..15
    const int b   = seg >> 2, s = seg & 3;

    __shared__ ushort tile[64][65];

    const int t  = threadIdx.x;
    const int r  = t >> 2;             // 0..63
    const int cq = (t & 3) << 4;       // 0,16,32,48

    union U8 { bf16x8 v; ushort u[8]; };

    {
        const int  i   = it * 64 + r;
        const long tok = (long)s * SEG_W + off + 4L * i;
        const float* src = x + ((long)b * NTOK + tok) * D_MODEL + dt * 64 + cq;
        float4 f0 = ((const float4*)src)[0];
        float4 f1 = ((const float4*)src)[1];
        float4 f2 = ((const float4*)src)[2];
        float4 f3 = ((const float4*)src)[3];
        U8 lo, hi, ls, hs;
        lo.v[0]=(bf16_t)f0.x; lo.v[1]=(bf16_t)f0.y; lo.v[2]=(bf16_t)f0.z; lo.v[3]=(bf16_t)f0.w;
        lo.v[4]=(bf16_t)f1.x; lo.v[5]=(bf16_t)f1.y; lo.v[6]=(bf16_t)f1.z; lo.v[7]=(bf16_t)f1.w;
        hi.v[0]=(bf16_t)f2.x; hi.v[1]=(bf16_t)f2.y; hi.v[2]=(bf16_t)f2.z; hi.v[3]=(bf16_t)f2.w;
        hi.v[4]=(bf16_t)f3.x; hi.v[5]=(bf16_t)f3.y; hi.v[6]=(bf16_t)f3.z; hi.v[7]=(bf16_t)f3.w;
        ls.v[0]=(bf16_t)(f0.x*QK_SCALE); ls.v[1]=(bf16_t)(f0.y*QK_SCALE);
        ls.v[2]=(bf16_t)(f0.z*QK_SCALE); ls.v[3]=(bf16_t)(f0.w*QK_SCALE);
        ls.v[4]=(bf16_t)(f1.x*QK_SCALE); ls.v[5]=(bf16_t)(f1.y*QK_SCALE);
        ls.v[6]=(bf16_t)(f1.z*QK_SCALE); ls.v[7]=(bf16_t)(f1.w*QK_SCALE);
        hs.v[0]=(bf16_t)(f2.x*QK_SCALE); hs.v[1]=(bf16_t)(f2.y*QK_SCALE);
        hs.v[2]=(bf16_t)(f2.z*QK_SCALE); hs.v[3]=(bf16_t)(f2.w*QK_SCALE);
        hs.v[4]=(bf16_t)(f3.x*QK_SCALE); hs.v[5]=(bf16_t)(f3.y*QK_SCALE);
        hs.v[6]=(bf16_t)(f3.z*QK_SCALE); hs.v[7]=(bf16_t)(f3.w*QK_SCALE);
        bf16_t* dstg = xg + ((long)seg * M_SUB + i) * D_MODEL + dt * 64 + cq;
        *(bf16x8*)(dstg)     = ls.v;
        *(bf16x8*)(dstg + 8) = hs.v;
        #pragma unroll
        for (int j = 0; j < 8; ++j) { tile[r][cq + j] = lo.u[j]; tile[r][cq + 8 + j] = hi.u[j]; }
    }
    __syncthreads();
    {
        const int dc = r;
        const int iq = cq;
        U8 o0, o1;
        #pragma unroll
        for (int j = 0; j < 8; ++j) { o0.u[j] = tile[iq + j][dc]; o1.u[j] = tile[iq + 8 + j][dc]; }
        bf16_t* dstT = xgT + ((long)seg * D_MODEL + dt * 64 + dc) * M_SUB + it * 64 + iq;
        *(bf16x8*)(dstT)     = o0.v;
        *(bf16x8*)(dstT + 8) = o1.v;
    }
}

// ---------------------------------------------------------------------------
// K2: QK GEMM. S[seg][q][k] = sum_d xg[q][d]*xg[k][d] (pre-scaled), bf16 out.
// BM=64, BN=128, BK=64. grid = 512 blocks, 512 threads (8 waves).
// Wave w: wr=w>>2 (32-row half), wc=w&3 (32-col quarter); 2x2 MFMA tiles.
// XOR chunk swizzle: global 16B-chunk c of LDS row r lives at slot c^(r&7).
// ---------------------------------------------------------------------------
__global__ __launch_bounds__(512) void qk_kernel(
    const bf16_t* __restrict__ xg, bf16_t* __restrict__ S)
{
    const int bid = blockIdx.x;
    const int seg = bid >> 5;
    const int mt  = (bid >> 2) & 7;
    const int nt  = bid & 3;

    const int tid  = threadIdx.x;
    const int w    = tid >> 6;          // 0..7
    const int lane = tid & 63;
    const int l16  = lane & 15;
    const int quad = lane >> 4;
    const int wr   = w >> 2, wc = w & 3;
    const int row8 = lane >> 3;         // 0..7 row within 8-row round
    const int cswz = ((lane & 7) ^ row8) * 8;   // fetch chunk, slot = lane&7
    const int rsw  = l16 & 7;           // fragment-row swizzle key

    __shared__ alignas(16) bf16_t As[64 * 64];    // 8 KB
    __shared__ alignas(16) bf16_t Bs[128 * 64];   // 16 KB

    const bf16_t* xseg = xg + (long)seg * M_SUB * D_MODEL;

    // staging: wave w loads A rows w*8..w*8+7 (1 gload) and B rows
    // w*16..w*16+15 (2 gloads). row&7 == row8 for all (8-aligned bases).
    const bf16_t* ga  = xseg + (long)(mt * 64 + w * 8 + row8) * D_MODEL + cswz;
    const bf16_t* gb0 = xseg + (long)(nt * 128 + w * 16 + row8) * D_MODEL + cswz;
    const bf16_t* gb1 = gb0 + 8 * D_MODEL;
    bf16_t* la  = &As[(w * 8) * 64];
    bf16_t* lb0 = &Bs[(w * 16 + 0) * 64];
    bf16_t* lb1 = &Bs[(w * 16 + 8) * 64];

    floatx4 acc[2][2];
    #pragma unroll
    for (int i = 0; i < 2; ++i)
        #pragma unroll
        for (int j = 0; j < 2; ++j) acc[i][j] = (floatx4){0.f, 0.f, 0.f, 0.f};

    for (int kk = 0; kk < D_MODEL; kk += 64) {
        __syncthreads();
        gload16(ga  + kk, la);
        gload16(gb0 + kk, lb0); gload16(gb1 + kk, lb1);
        __syncthreads();

        #pragma unroll
        for (int ks = 0; ks < 2; ++ks) {
            bf16x8 Af[2], Bf[2];
            #pragma unroll
            for (int m2 = 0; m2 < 2; ++m2) {
                const int row = wr * 32 + m2 * 16 + l16;
                Af[m2] = *(const bf16x8*)&As[row * 64 + (((ks * 4 + quad) ^ rsw) * 8)];
            }
            #pragma unroll
            for (int n2 = 0; n2 < 2; ++n2) {
                const int row = wc * 32 + n2 * 16 + l16;
                Bf[n2] = *(const bf16x8*)&Bs[row * 64 + (((ks * 4 + quad) ^ rsw) * 8)];
            }
            #pragma unroll
            for (int m2 = 0; m2 < 2; ++m2)
                #pragma unroll
                for (int n2 = 0; n2 < 2; ++n2)
                    acc[m2][n2] = __builtin_amdgcn_mfma_f32_16x16x32_bf16(Af[m2], Bf[n2], acc[m2][n2], 0, 0, 0);
        }
    }

    bf16_t* Sseg = S + (long)seg * M_SUB * M_SUB;
    #pragma unroll
    for (int m2 = 0; m2 < 2; ++m2) {
        const int qrow = mt * 64 + wr * 32 + m2 * 16 + quad * 4;
        #pragma unroll
        for (int n2 = 0; n2 < 2; ++n2) {
            const int col = nt * 128 + wc * 32 + n2 * 16 + l16;
            #pragma unroll
            for (int rg = 0; rg < 4; ++rg)
                Sseg[(long)(qrow + rg) * M_SUB + col] = (bf16_t)acc[m2][n2][rg];
        }
    }
}

// ---------------------------------------------------------------------------
// K3: row-wise softmax in-place on S (bf16). 1 wave per 512-row.
// ---------------------------------------------------------------------------
__global__ __launch_bounds__(256) void softmax_kernel(bf16_t* __restrict__ S)
{
    const int row  = blockIdx.x * 4 + (threadIdx.x >> 6);
    const int lane = threadIdx.x & 63;
    bf16_t* p = S + (long)row * M_SUB + lane * 8;
    bf16x8 v = *(const bf16x8*)p;
    float f[8];
    #pragma unroll
    for (int j = 0; j < 8; ++j) f[j] = (float)v[j];
    float m = f[0];
    #pragma unroll
    for (int j = 1; j < 8; ++j) m = fmaxf(m, f[j]);
    #pragma unroll
    for (int d = 1; d < 64; d <<= 1) m = fmaxf(m, __shfl_xor(m, d, 64));
    float sum = 0.f;
    #pragma unroll
    for (int j = 0; j < 8; ++j) { f[j] = __expf(f[j] - m); sum += f[j]; }
    #pragma unroll
    for (int d = 1; d < 64; d <<= 1) sum += __shfl_xor(sum, d, 64);
    const float inv = 1.0f / sum;
    #pragma unroll
    for (int j = 0; j < 8; ++j) v[j] = (bf16_t)(f[j] * inv);
    *(bf16x8*)p = v;
}

// ---------------------------------------------------------------------------
// K4: PV GEMM. out[tok][d] = sum_k P[q][k]*V[k][d], V^T = xgT.
// BM=BN=128, BK=64. grid = 16 segs * 4 mt * 8 nt = 512 blocks, 512 threads.
// Wave w: wr=w>>1 (32-row quarter), wc=w&1 (64-col half); 2x4 MFMA tiles.
// Epilogue: nontemporal scatter + zero-fill of 3*128 non-idx rows x 128 cols.
// ---------------------------------------------------------------------------
__global__ __launch_bounds__(512) void pv_kernel(
    const bf16_t* __restrict__ P, const bf16_t* __restrict__ xgT,
    const int* __restrict__ hidp, float* __restrict__ out)
{
    const int off = ((hidp[0] % RATE) + RATE) % RATE;
    const int bid = blockIdx.x;
    const int seg = bid >> 5;          // 0..15
    const int mt  = (bid >> 3) & 3;    // 0..3  (128-row q-tile)
    const int nt  = bid & 7;           // 0..7  (128-col d-tile)
    const int b   = seg >> 2, s = seg & 3;

    const int tid  = threadIdx.x;
    const int w    = tid >> 6;          // 0..7
    const int lane = tid & 63;
    const int l16  = lane & 15;
    const int quad = lane >> 4;
    const int wr   = w >> 1, wc = w & 1;
    const int row8 = lane >> 3;
    const int cswz = ((lane & 7) ^ row8) * 8;
    const int rsw  = l16 & 7;

    __shared__ alignas(16) bf16_t As[128 * 64];   // 16 KB
    __shared__ alignas(16) bf16_t Bs[128 * 64];   // 16 KB

    const bf16_t* Aseg = P   + (long)seg * M_SUB * M_SUB  + (long)mt * 128 * M_SUB;
    const bf16_t* Bseg = xgT + (long)seg * D_MODEL * M_SUB + (long)nt * 128 * M_SUB;

    // staging: wave w loads A rows w*16..+15 (2 gloads) and B rows w*16..+15.
    const bf16_t* ga0 = Aseg + (long)(w * 16 + row8) * M_SUB + cswz;
    const bf16_t* ga1 = ga0 + 8 * M_SUB;
    const bf16_t* gb0 = Bseg + (long)(w * 16 + row8) * M_SUB + cswz;
    const bf16_t* gb1 = gb0 + 8 * M_SUB;
    bf16_t* la0 = &As[(w * 16 + 0) * 64];
    bf16_t* la1 = &As[(w * 16 + 8) * 64];
    bf16_t* lb0 = &Bs[(w * 16 + 0) * 64];
    bf16_t* lb1 = &Bs[(w * 16 + 8) * 64];

    floatx4 acc[2][4];
    #pragma unroll
    for (int i = 0; i < 2; ++i)
        #pragma unroll
        for (int j = 0; j < 4; ++j) acc[i][j] = (floatx4){0.f, 0.f, 0.f, 0.f};

    for (int kk = 0; kk < M_SUB; kk += 64) {
        __syncthreads();
        gload16(ga0 + kk, la0); gload16(ga1 + kk, la1);
        gload16(gb0 + kk, lb0); gload16(gb1 + kk, lb1);
        __syncthreads();

        #pragma unroll
        for (int ks = 0; ks < 2; ++ks) {
            bf16x8 Af[2], Bf[4];
            #pragma unroll
            for (int m2 = 0; m2 < 2; ++m2) {
                const int row = wr * 32 + m2 * 16 + l16;
                Af[m2] = *(const bf16x8*)&As[row * 64 + (((ks * 4 + quad) ^ rsw) * 8)];
            }
            #pragma unroll
            for (int n2 = 0; n2 < 4; ++n2) {
                const int row = wc * 64 + n2 * 16 + l16;
                Bf[n2] = *(const bf16x8*)&Bs[row * 64 + (((ks * 4 + quad) ^ rsw) * 8)];
            }
            #pragma unroll
            for (int m2 = 0; m2 < 2; ++m2)
                #pragma unroll
                for (int n2 = 0; n2 < 4; ++n2)
                    acc[m2][n2] = __builtin_amdgcn_mfma_f32_16x16x32_bf16(Af[m2], Bf[n2], acc[m2][n2], 0, 0, 0);
        }
    }

    // ---- result scatter (nontemporal: not re-read)
    float* obase = out + (long)b * NTOK * D_MODEL;
    #pragma unroll
    for (int m2 = 0; m2 < 2; ++m2) {
        const int qrow0 = mt * 128 + wr * 32 + m2 * 16 + quad * 4;
        #pragma unroll
        for (int rg = 0; rg < 4; ++rg) {
            const long tok = (long)s * SEG_W + off + 4L * (qrow0 + rg);
            float* orow = obase + tok * D_MODEL;
            #pragma unroll
            for (int n2 = 0; n2 < 4; ++n2) {
                const int d = nt * 128 + wc * 64 + n2 * 16 + l16;
                __builtin_nontemporal_store(acc[m2][n2][rg], &orow[d]);
            }
        }
    }

    // ---- fused zero-fill: 3*128 non-idx rows x this block's 128 cols
    {
        const floatx4 z = {0.f, 0.f, 0.f, 0.f};
        const int zr = tid >> 5;        // 0..15
        const int zc = tid & 31;        // float4 chunk within 128 cols
        #pragma unroll 4
        for (int p = 0; p < 24; ++p) {
            const int j = p * 16 + zr;  // 0..383
            const int q = j / 3, e = j % 3;
            const int delta = e + (e >= off ? 1 : 0);
            const long tok = (long)s * SEG_W + 4L * (mt * 128 + q) + delta;
            float* dst = obase + tok * D_MODEL + nt * 128 + zc * 4;
            __builtin_nontemporal_store(z, (floatx4*)dst);
        }
    }
}

extern "C" void kernel_launch(void* const* d_in, const int* in_sizes, int n_in,
                              void* d_out, int out_size, void* d_ws, size_t ws_size,
                              hipStream_t stream) {
    const float* x   = (const float*)d_in[0];
    const int*   hid = (const int*)d_in[1];
    float*       out = (float*)d_out;
    bf16_t* xg  = (bf16_t*)d_ws;
    bf16_t* xgT = xg + XG_ELEMS;
    bf16_t* S   = xgT + XG_ELEMS;     // total ws: 2*16.78 + 8.39 = 41.9 MB

    gather_kernel<<<dim3(2048), dim3(256), 0, stream>>>(x, hid, xg, xgT);
    qk_kernel<<<dim3(512), dim3(512), 0, stream>>>(xg, S);
    softmax_kernel<<<dim3(2048), dim3(256), 0, stream>>>(S);
    pv_kernel<<<dim3(512), dim3(512), 0, stream>>>(S, xgT, hid, out);
}